// Round 7
// baseline (66.437 us; speedup 1.0000x reference)
//
#include <hip/hip_runtime.h>
#include <hip/hip_bf16.h>

#define HDIM 768
#define NSUP 128
#define NTOT 384
#define NREL 8
#define WPLANE (HDIM*HDIM)
#define W1LD  (2*HDIM)

typedef unsigned short u16;
typedef __attribute__((ext_vector_type(8))) short bf16x8;
typedef __attribute__((ext_vector_type(4))) float f32x4;
typedef _Float16 h2v __attribute__((ext_vector_type(2)));

__device__ __forceinline__ u16 f2b(float f){
  unsigned x = __float_as_uint(f);
  return (u16)((x + 0x7fffu + ((x>>16)&1u)) >> 16);
}
__device__ __forceinline__ float b2f(u16 u){ return __uint_as_float(((unsigned)u)<<16); }
__device__ __forceinline__ u16 f2h_bits(float f){
  _Float16 h = (_Float16)f;
  return __builtin_bit_cast(unsigned short, h);
}

__device__ __forceinline__ const float* emb_row(const float* sup, const float* qry, int row){
  return row < NSUP ? sup + (size_t)row*HDIM : qry + (size_t)(row-NSUP)*HDIM;
}

// ---------------- prep_k: embB, wsumB, simW1B, divW1B (bf16), bsum (f32) ----------------
__global__ __launch_bounds__(256) void prep_k(
    const float* __restrict__ sup, const float* __restrict__ qry,
    const float* __restrict__ relW, const float* __restrict__ relB,
    const float* __restrict__ simW1, const float* __restrict__ divW1,
    u16* __restrict__ embB, u16* __restrict__ wsumB,
    u16* __restrict__ simW1B, u16* __restrict__ divW1B, float* __restrict__ bsum){
  int u = blockIdx.x*256 + threadIdx.x;
  if (u < 147456){
    int f = u*4;
    float4 s = make_float4(0.f,0.f,0.f,0.f);
#pragma unroll
    for (int r=0;r<NREL;r++){
      float4 v = *reinterpret_cast<const float4*>(relW + (size_t)r*WPLANE + f);
      s.x+=v.x; s.y+=v.y; s.z+=v.z; s.w+=v.w;
    }
    ushort4 o; o.x=f2b(s.x); o.y=f2b(s.y); o.z=f2b(s.z); o.w=f2b(s.w);
    *reinterpret_cast<ushort4*>(wsumB + f) = o;
  } else if (u < 221184){
    int f = (u - 147456)*4;
    const float* src = (f < NSUP*HDIM) ? (sup + f) : (qry + f - NSUP*HDIM);
    float4 v = *reinterpret_cast<const float4*>(src);
    ushort4 o; o.x=f2b(v.x); o.y=f2b(v.y); o.z=f2b(v.z); o.w=f2b(v.w);
    *reinterpret_cast<ushort4*>(embB + f) = o;
  } else if (u < 516096){
    int f = (u - 221184)*4;
    float4 v = *reinterpret_cast<const float4*>(simW1 + f);
    ushort4 o; o.x=f2b(v.x); o.y=f2b(v.y); o.z=f2b(v.z); o.w=f2b(v.w);
    *reinterpret_cast<ushort4*>(simW1B + f) = o;
  } else {
    int f = (u - 516096)*4;
    float4 v = *reinterpret_cast<const float4*>(divW1 + f);
    ushort4 o; o.x=f2b(v.x); o.y=f2b(v.y); o.z=f2b(v.z); o.w=f2b(v.w);
    *reinterpret_cast<ushort4*>(divW1B + f) = o;
  }
  if (blockIdx.x==0 && threadIdx.x < HDIM/4){
    int c = threadIdx.x*4;
    float4 s = make_float4(0.f,0.f,0.f,0.f);
#pragma unroll
    for (int r=0;r<NREL;r++){
      float4 v = *reinterpret_cast<const float4*>(relB + r*HDIM + c);
      s.x+=v.x; s.y+=v.y; s.z+=v.z; s.w+=v.w;
    }
    *reinterpret_cast<float4*>(bsum + c) = s;
  }
}

// ---------------- gemm5v3_k: chunked-prefetch MFMA; L/R out f16 (b1 folded into L) ----------------
struct G5M3 {
  const u16* WB[5];
  int ldw[5];
  int koff[5];
  const float* b1f[4];   // z=0: simb1, z=2: divb1, else null
  u16* outH[4];          // f16 outputs
  float* outF;
  const float* bsum;
};

__global__ __launch_bounds__(512) void gemm5v3_k(const u16* __restrict__ embB, G5M3 ga){
  __shared__ f32x4 red[4][4][64];   // 16KB
  int z = blockIdx.z;
  int t = threadIdx.x, lane = t&63, wid = t>>6;
  int q = wid & 3, kh = wid >> 2;
  int m0 = blockIdx.y*64 + (q&1)*32;
  int n0 = blockIdx.x*64 + (q>>1)*32;
  int l15 = lane & 15;
  int kl = (lane>>4)*8;
  int kbase = kh*384;
  int ldw = ga.ldw[z];
  const u16* A0 = embB + (size_t)(m0 + l15)*HDIM + kbase + kl;
  const u16* A1 = A0 + 16*HDIM;
  const u16* B0 = ga.WB[z] + (size_t)(n0 + l15)*ldw + ga.koff[z] + kbase + kl;
  const u16* B1 = B0 + 16*ldw;
  f32x4 acc00={0,0,0,0}, acc01={0,0,0,0}, acc10={0,0,0,0}, acc11={0,0,0,0};

#pragma unroll
  for (int kc=0; kc<384; kc+=128){
    bf16x8 a0v[4], a1v[4], b0v[4], b1v[4];
#pragma unroll
    for (int s=0;s<4;s++){
      a0v[s] = *reinterpret_cast<const bf16x8*>(A0 + kc + 32*s);
      a1v[s] = *reinterpret_cast<const bf16x8*>(A1 + kc + 32*s);
      b0v[s] = *reinterpret_cast<const bf16x8*>(B0 + kc + 32*s);
      b1v[s] = *reinterpret_cast<const bf16x8*>(B1 + kc + 32*s);
    }
#pragma unroll
    for (int s=0;s<4;s++){
      acc00 = __builtin_amdgcn_mfma_f32_16x16x32_bf16(a0v[s], b0v[s], acc00, 0, 0, 0);
      acc10 = __builtin_amdgcn_mfma_f32_16x16x32_bf16(a1v[s], b0v[s], acc10, 0, 0, 0);
      acc01 = __builtin_amdgcn_mfma_f32_16x16x32_bf16(a0v[s], b1v[s], acc01, 0, 0, 0);
      acc11 = __builtin_amdgcn_mfma_f32_16x16x32_bf16(a1v[s], b1v[s], acc11, 0, 0, 0);
    }
  }

  if (kh){
    red[q][0][lane] = acc00;
    red[q][1][lane] = acc01;
    red[q][2][lane] = acc10;
    red[q][3][lane] = acc11;
  }
  __syncthreads();
  if (!kh){
    acc00 += red[q][0][lane];
    acc01 += red[q][1][lane];
    acc10 += red[q][2][lane];
    acc11 += red[q][3][lane];
    int r0 = (lane>>4)*4;
    if (z < 4){
      u16* outp = ga.outH[z];
      float bn0 = 0.f, bn1 = 0.f;
      const float* b1f = ga.b1f[z];
      if (b1f){ bn0 = b1f[n0 + l15]; bn1 = b1f[n0 + 16 + l15]; }
#pragma unroll
      for (int r=0;r<4;r++){
        outp[(size_t)(m0 + r0 + r)*HDIM      + n0 + l15]      = f2h_bits(acc00[r] + bn0);
        outp[(size_t)(m0 + r0 + r)*HDIM      + n0 + 16 + l15] = f2h_bits(acc01[r] + bn1);
        outp[(size_t)(m0 + 16 + r0 + r)*HDIM + n0 + l15]      = f2h_bits(acc10[r] + bn0);
        outp[(size_t)(m0 + 16 + r0 + r)*HDIM + n0 + 16 + l15] = f2h_bits(acc11[r] + bn1);
      }
    } else {
      float* outp = ga.outF;
      float bn0 = ga.bsum[n0 + l15];
      float bn1 = ga.bsum[n0 + 16 + l15];
#pragma unroll
      for (int r=0;r<4;r++){
        outp[(size_t)(m0 + r0 + r)*HDIM      + n0 + l15]      = (acc00[r] + bn0)*0.125f;
        outp[(size_t)(m0 + r0 + r)*HDIM      + n0 + 16 + l15] = (acc01[r] + bn1)*0.125f;
        outp[(size_t)(m0 + 16 + r0 + r)*HDIM + n0 + l15]      = (acc10[r] + bn0)*0.125f;
        outp[(size_t)(m0 + 16 + r0 + r)*HDIM + n0 + 16 + l15] = (acc11[r] + bn1)*0.125f;
      }
    }
  }
}

// ---------------- pair3_k: f16 packed math, 8 i-rows/block ----------------
// m[i,j] = sum_k relu(L'[i,k] + R[j,k]) * w2[k] + b2   (L' has b1 folded, f16)
struct P3Args {
  const u16* L[2]; const u16* R[2];       // f16-bit matrices [384][768]
  const float* w2[2]; const float* b2[2];
  float* out[2];
};

__global__ __launch_bounds__(256) void pair3_k(P3Args pa){
  int z = blockIdx.z;
  int i0 = blockIdx.x*8, jt = blockIdx.y;
  __shared__ u16 Lh[8][768];
  __shared__ u16 w2h[768];
  int t = threadIdx.x;
  const u16* __restrict__ L = pa.L[z];
  for (int idx=t; idx<1536; idx+=256){
    int ii = idx/192, qq = idx - ii*192;
    reinterpret_cast<ushort4*>(&Lh[ii][0])[qq] =
        reinterpret_cast<const ushort4*>(L + (size_t)(i0+ii)*HDIM)[qq];
  }
  if (t < 192){
    float4 wv = reinterpret_cast<const float4*>(pa.w2[z])[t];
    ushort4 o; o.x=f2h_bits(wv.x); o.y=f2h_bits(wv.y); o.z=f2h_bits(wv.z); o.w=f2h_bits(wv.w);
    reinterpret_cast<ushort4*>(w2h)[t] = o;
  }
  __syncthreads();
  int w = t>>6, l = t&63;
  int jb = jt*32 + w*8;
  const u16* __restrict__ R = pa.R[z];
  float b2v = pa.b2[z][0];
  float* outp = pa.out[z];
  const h2v hz = {(_Float16)0.f, (_Float16)0.f};

  const uint2* Rr = reinterpret_cast<const uint2*>(R + (size_t)jb*HDIM);
  uint2 r0 = Rr[l], r1 = Rr[64+l], r2 = Rr[128+l];
  for (int tt=0;tt<8;tt++){
    int j = jb + tt;
    uint2 p0, p1, p2;
    if (tt < 7){
      const uint2* Rn = reinterpret_cast<const uint2*>(R + (size_t)(j+1)*HDIM);
      p0 = Rn[l]; p1 = Rn[64+l]; p2 = Rn[128+l];
    }
    float acc[8] = {0.f,0.f,0.f,0.f,0.f,0.f,0.f,0.f};
    uint2 rr[3] = {r0, r1, r2};
#pragma unroll
    for (int u=0;u<3;u++){
      h2v rA = __builtin_bit_cast(h2v, rr[u].x);
      h2v rB = __builtin_bit_cast(h2v, rr[u].y);
      int kq = u*64 + l;
      uint2 wv2 = reinterpret_cast<const uint2*>(w2h)[kq];
      h2v wA = __builtin_bit_cast(h2v, wv2.x);
      h2v wB = __builtin_bit_cast(h2v, wv2.y);
#pragma unroll
      for (int ii=0;ii<8;ii++){
        uint2 lv2 = reinterpret_cast<const uint2*>(&Lh[ii][0])[kq];
        h2v sA = __builtin_bit_cast(h2v, lv2.x) + rA;
        h2v sB = __builtin_bit_cast(h2v, lv2.y) + rB;
        sA = __builtin_elementwise_max(sA, hz);
        sB = __builtin_elementwise_max(sB, hz);
        acc[ii] = __builtin_amdgcn_fdot2(sA, wA, acc[ii], false);
        acc[ii] = __builtin_amdgcn_fdot2(sB, wB, acc[ii], false);
      }
    }
#pragma unroll
    for (int ii=0;ii<8;ii++){
      float a = acc[ii];
#pragma unroll
      for (int m=32;m>=1;m>>=1) a += __shfl_xor(a, m, 64);
      if (l == ii){
        float v = a + b2v;
        if (i0+ii == j) v = 0.f;
        outp[(size_t)(i0+ii)*NTOT + j] = v;
      }
    }
    r0 = p0; r1 = p1; r2 = p2;
  }
}

// ================= fallback (proven zero-ws path) =================
__global__ __launch_bounds__(256) void prop_k(
    const float* __restrict__ sup, const float* __restrict__ qry,
    const float* __restrict__ relW, const float* __restrict__ relB,
    float* __restrict__ outp){
  __shared__ float As[16][68];
  __shared__ float Bs[16][68];
  int t = threadIdx.x;
  int m0 = blockIdx.y*64, n0 = blockIdx.x*64;
  int lm = t>>2, lk = (t&3)<<2;
  int tx = t&15, ty = t>>4;
  float acc[4][4] = {{0,0,0,0},{0,0,0,0},{0,0,0,0},{0,0,0,0}};
  const float* Aptr = emb_row(sup, qry, m0+lm) + lk;
  const float* Bptr = relW + (size_t)(n0+lm)*HDIM + lk;
  for (int k0=0;k0<HDIM;k0+=16){
    float4 av = *reinterpret_cast<const float4*>(Aptr + k0);
    float4 bs = make_float4(0.f,0.f,0.f,0.f);
#pragma unroll
    for (int r=0;r<NREL;r++){
      float4 bv = *reinterpret_cast<const float4*>(Bptr + (size_t)r*WPLANE + k0);
      bs.x += bv.x; bs.y += bv.y; bs.z += bv.z; bs.w += bv.w;
    }
    __syncthreads();
    As[lk+0][lm]=av.x; As[lk+1][lm]=av.y; As[lk+2][lm]=av.z; As[lk+3][lm]=av.w;
    Bs[lk+0][lm]=bs.x; Bs[lk+1][lm]=bs.y; Bs[lk+2][lm]=bs.z; Bs[lk+3][lm]=bs.w;
    __syncthreads();
#pragma unroll
    for (int kk=0;kk<16;kk++){
      float4 a4 = *reinterpret_cast<const float4*>(&As[kk][ty<<2]);
      float4 b4 = *reinterpret_cast<const float4*>(&Bs[kk][tx<<2]);
      float ar[4]={a4.x,a4.y,a4.z,a4.w};
      float br[4]={b4.x,b4.y,b4.z,b4.w};
#pragma unroll
      for (int i2=0;i2<4;i2++)
#pragma unroll
        for (int j2=0;j2<4;j2++)
          acc[i2][j2] = fmaf(ar[i2], br[j2], acc[i2][j2]);
    }
  }
#pragma unroll
  for (int j2=0;j2<4;j2++){
    int n = n0 + (tx<<2) + j2;
    float bias = 0.f;
#pragma unroll
    for (int r=0;r<NREL;r++) bias += relB[r*HDIM + n];
#pragma unroll
    for (int i2=0;i2<4;i2++){
      int m = m0 + (ty<<2) + i2;
      outp[(size_t)m*HDIM + n] = (acc[i2][j2] + bias) * 0.125f;
    }
  }
}

struct NWArgs {
  const float* W1[2]; const float* b1[2]; const float* w2[2]; const float* b2[2];
  float* out[2];
};

__global__ __launch_bounds__(256) void pair_nows_k(
    const float* __restrict__ sup, const float* __restrict__ qry, NWArgs na){
  int z = blockIdx.z, i0 = blockIdx.x*32, j0 = blockIdx.y*32;
  __shared__ u16 Lt[32][768];
  __shared__ float Rj[768];
  __shared__ float b1s[768];
  __shared__ float w2s[768];
  const float* __restrict__ W1 = na.W1[z];
  int t = threadIdx.x;
  for (int k=t;k<768;k+=256){ b1s[k]=na.b1[z][k]; w2s[k]=na.w2[z][k]; }
  for (int e=t; e<32*768; e+=256){
    int ii = e/768, k = e - ii*768;
    const float4* er = reinterpret_cast<const float4*>(emb_row(sup, qry, i0+ii));
    const float4* wr = reinterpret_cast<const float4*>(W1 + (size_t)k*W1LD);
    float s = 0.f;
    for (int h=0;h<192;h++){
      float4 a = er[h], b = wr[h];
      s += a.x*b.x + a.y*b.y + a.z*b.z + a.w*b.w;
    }
    Lt[ii][k] = f2b(s);
  }
  float b2v = na.b2[z][0];
  int w = t>>6, l = t&63;
  float* outp = na.out[z];
  for (int jj=0;jj<32;jj++){
    int j = j0 + jj;
    const float4* ejr = reinterpret_cast<const float4*>(emb_row(sup, qry, j));
    __syncthreads();
    for (int k=t;k<768;k+=256){
      const float4* wr = reinterpret_cast<const float4*>(W1 + (size_t)k*W1LD + HDIM);
      float s = 0.f;
      for (int h=0;h<192;h++){
        float4 a = ejr[h], b = wr[h];
        s += a.x*b.x + a.y*b.y + a.z*b.z + a.w*b.w;
      }
      Rj[k] = s;
    }
    __syncthreads();
    for (int q=0;q<8;q++){
      int ii = (w<<3) + q;
      float acc = 0.f;
#pragma unroll
      for (int u=0;u<12;u++){
        int k = l + (u<<6);
        acc = fmaf(fmaxf(b2f(Lt[ii][k]) + Rj[k] + b1s[k], 0.f), w2s[k], acc);
      }
#pragma unroll
      for (int m=32;m>=1;m>>=1) acc += __shfl_xor(acc, m, 64);
      if (l==0){
        int i = i0 + ii;
        float v = acc + b2v;
        if (i==j) v = 0.f;
        outp[(size_t)i*NTOT + j] = v;
      }
    }
  }
}

extern "C" void kernel_launch(void* const* d_in, const int* in_sizes, int n_in,
                              void* d_out, int out_size, void* d_ws, size_t ws_size,
                              hipStream_t stream) {
  const float* sup   = (const float*)d_in[0];
  // d_in[1] = support_labels (unused)
  const float* qry   = (const float*)d_in[2];
  const float* simW1 = (const float*)d_in[3];
  const float* simb1 = (const float*)d_in[4];
  const float* simw2 = (const float*)d_in[5];
  const float* simb2 = (const float*)d_in[6];
  const float* divW1 = (const float*)d_in[7];
  const float* divb1 = (const float*)d_in[8];
  const float* divw2 = (const float*)d_in[9];
  const float* divb2 = (const float*)d_in[10];
  const float* relW  = (const float*)d_in[11];
  const float* relB  = (const float*)d_in[12];
  float* out = (float*)d_out;
  float* outSim = out + (size_t)NTOT*HDIM;
  float* outDiv = outSim + (size_t)NTOT*NTOT;

  const size_t EMBB = (size_t)NTOT*HDIM*2;
  const size_t WSB  = (size_t)WPLANE*2;
  const size_t W1B  = (size_t)HDIM*W1LD*2;
  const size_t LRB  = (size_t)NTOT*HDIM*2;
  const size_t NEED = EMBB + WSB + 2*W1B + 4096 + 4*LRB;   // 8,851,456

  if (ws_size >= NEED){
    char* ws = (char*)d_ws;
    u16*   embB   = (u16*)(ws);
    u16*   wsumB  = (u16*)(ws + EMBB);
    u16*   simW1B = (u16*)(ws + EMBB + WSB);
    u16*   divW1B = (u16*)(ws + EMBB + WSB + W1B);
    float* bsum   = (float*)(ws + EMBB + WSB + 2*W1B);
    u16*   Ls     = (u16*)(ws + EMBB + WSB + 2*W1B + 4096);
    u16*   Rs     = (u16*)((char*)Ls + LRB);
    u16*   Ld     = (u16*)((char*)Rs + LRB);
    u16*   Rd     = (u16*)((char*)Ld + LRB);

    prep_k<<<dim3(3168), dim3(256), 0, stream>>>(
        sup, qry, relW, relB, simW1, divW1, embB, wsumB, simW1B, divW1B, bsum);

    G5M3 ga;
    ga.WB[0]=simW1B; ga.ldw[0]=W1LD; ga.koff[0]=0;    ga.b1f[0]=simb1;   ga.outH[0]=Ls;
    ga.WB[1]=simW1B; ga.ldw[1]=W1LD; ga.koff[1]=HDIM; ga.b1f[1]=nullptr; ga.outH[1]=Rs;
    ga.WB[2]=divW1B; ga.ldw[2]=W1LD; ga.koff[2]=0;    ga.b1f[2]=divb1;   ga.outH[2]=Ld;
    ga.WB[3]=divW1B; ga.ldw[3]=W1LD; ga.koff[3]=HDIM; ga.b1f[3]=nullptr; ga.outH[3]=Rd;
    ga.WB[4]=wsumB;  ga.ldw[4]=HDIM; ga.koff[4]=0;
    ga.outF=out; ga.bsum=bsum;
    gemm5v3_k<<<dim3(12,6,5), dim3(512), 0, stream>>>(embB, ga);

    P3Args pa;
    pa.L[0]=Ls; pa.R[0]=Rs; pa.w2[0]=simw2; pa.b2[0]=simb2; pa.out[0]=outSim;
    pa.L[1]=Ld; pa.R[1]=Rd; pa.w2[1]=divw2; pa.b2[1]=divb2; pa.out[1]=outDiv;
    pair3_k<<<dim3(NTOT/8,12,2), dim3(256), 0, stream>>>(pa);
  } else {
    prop_k<<<dim3(12,6), dim3(256), 0, stream>>>(sup, qry, relW, relB, out);
    NWArgs na;
    na.W1[0]=simW1; na.b1[0]=simb1; na.w2[0]=simw2; na.b2[0]=simb2; na.out[0]=outSim;
    na.W1[1]=divW1; na.b1[1]=divb1; na.w2[1]=divw2; na.b2[1]=divb2; na.out[1]=outDiv;
    pair_nows_k<<<dim3(12,12,2), dim3(256), 0, stream>>>(sup, qry, na);
  }
}

// Round 8
// 62.044 us; speedup vs baseline: 1.0708x; 1.0708x over previous
//
#include <hip/hip_runtime.h>
#include <hip/hip_bf16.h>

#define HDIM 768
#define NSUP 128
#define NTOT 384
#define NREL 8
#define WPLANE (HDIM*HDIM)
#define W1LD  (2*HDIM)

typedef unsigned short u16;
typedef __attribute__((ext_vector_type(8))) short bf16x8;
typedef __attribute__((ext_vector_type(4))) float f32x4;
typedef _Float16 h2v __attribute__((ext_vector_type(2)));

// fragment-slot counts (1 slot = 64 lanes? no: 1 slot = one lane's bf16x8 = 16B)
// layout: [tile][kchunk(24)][frag(2)][lane(64)][elem(8)]
#define EMB_SLOTS   36864      // 12 tiles * 24 * 2 * 64
#define W_SLOTS     73728      // 24 tiles * 24 * 2 * 64
#define TILES_SLOTS (EMB_SLOTS + 5*W_SLOTS)   // emb + 4 W-halves + wsum = 405504

__device__ __forceinline__ u16 f2b(float f){
  unsigned x = __float_as_uint(f);
  return (u16)((x + 0x7fffu + ((x>>16)&1u)) >> 16);
}
__device__ __forceinline__ float b2f(u16 u){ return __uint_as_float(((unsigned)u)<<16); }
__device__ __forceinline__ u16 f2h_bits(float f){
  _Float16 h = (_Float16)f;
  return __builtin_bit_cast(unsigned short, h);
}
__device__ __forceinline__ unsigned pack2h(float a, float b){
  return (unsigned)f2h_bits(a) | ((unsigned)f2h_bits(b) << 16);
}

__device__ __forceinline__ const float* emb_row(const float* sup, const float* qry, int row){
  return row < NSUP ? sup + (size_t)row*HDIM : qry + (size_t)(row-NSUP)*HDIM;
}

// ---------------- prep2_k: build fragment-tiled bf16 buffers ----------------
// s in [0, TILES_SLOTS): lane=s&63, f=(s>>6)&1, t2=s>>7, kc=t2%24, tile=t2/24
// dst = tiles + s*8  (fully coalesced)
__global__ __launch_bounds__(256) void prep2_k(
    const float* __restrict__ sup, const float* __restrict__ qry,
    const float* __restrict__ relW, const float* __restrict__ relB,
    const float* __restrict__ simW1, const float* __restrict__ divW1,
    u16* __restrict__ tiles, float* __restrict__ bsum){
  int s = blockIdx.x*256 + threadIdx.x;
  if (s < TILES_SLOTS){
    int lane = s & 63, f = (s>>6) & 1;
    int t2 = s >> 7;
    int seg, loc;
    if (s < EMB_SLOTS){ seg = 0; loc = s; }
    else { int ls = s - EMB_SLOTS; seg = 1 + ls / W_SLOTS; loc = ls % W_SLOTS; }
    int lt2 = loc >> 7;
    int kc = lt2 % 24, tile = lt2 / 24;
    int row = tile*32 + f*16 + (lane & 15);
    int ksrc = kc*32 + (lane>>4)*8;
    float v[8];
    if (seg == 0){
      const float* src = emb_row(sup, qry, row) + ksrc;
      float4 a = *reinterpret_cast<const float4*>(src);
      float4 b = *reinterpret_cast<const float4*>(src + 4);
      v[0]=a.x; v[1]=a.y; v[2]=a.z; v[3]=a.w; v[4]=b.x; v[5]=b.y; v[6]=b.z; v[7]=b.w;
    } else if (seg <= 4){
      const float* base = (seg <= 2) ? simW1 : divW1;
      int koff = ((seg-1) & 1) ? HDIM : 0;
      const float* src = base + (size_t)row*W1LD + koff + ksrc;
      float4 a = *reinterpret_cast<const float4*>(src);
      float4 b = *reinterpret_cast<const float4*>(src + 4);
      v[0]=a.x; v[1]=a.y; v[2]=a.z; v[3]=a.w; v[4]=b.x; v[5]=b.y; v[6]=b.z; v[7]=b.w;
    } else {
      const float* src = relW + (size_t)row*HDIM + ksrc;
#pragma unroll
      for (int e=0;e<8;e++) v[e] = 0.f;
#pragma unroll
      for (int r=0;r<NREL;r++){
        float4 a = *reinterpret_cast<const float4*>(src + (size_t)r*WPLANE);
        float4 b = *reinterpret_cast<const float4*>(src + (size_t)r*WPLANE + 4);
        v[0]+=a.x; v[1]+=a.y; v[2]+=a.z; v[3]+=a.w; v[4]+=b.x; v[5]+=b.y; v[6]+=b.z; v[7]+=b.w;
      }
    }
    u16 o[8];
#pragma unroll
    for (int e=0;e<8;e++) o[e] = f2b(v[e]);
    ushort4* dst = reinterpret_cast<ushort4*>(tiles + (size_t)s*8);
    dst[0] = make_ushort4(o[0],o[1],o[2],o[3]);
    dst[1] = make_ushort4(o[4],o[5],o[6],o[7]);
  }
  if (blockIdx.x == 0 && threadIdx.x < HDIM/4){
    int c = threadIdx.x*4;
    float4 sbv = make_float4(0.f,0.f,0.f,0.f);
#pragma unroll
    for (int r=0;r<NREL;r++){
      float4 vv = *reinterpret_cast<const float4*>(relB + r*HDIM + c);
      sbv.x+=vv.x; sbv.y+=vv.y; sbv.z+=vv.z; sbv.w+=vv.w;
    }
    *reinterpret_cast<float4*>(bsum + c) = sbv;
  }
}

// ---------------- gemm5v4_k: coalesced fragment loads, in-block K-split ----------------
struct G5M4 {
  const float* b1f[4];   // z=0: simb1, z=2: divb1
  u16* outH[4];          // f16 L/R outputs
  float* outF;
  const float* bsum;
};

__global__ __launch_bounds__(512) void gemm5v4_k(const u16* __restrict__ tiles, G5M4 ga){
  __shared__ f32x4 red[4][4][64];   // 16KB
  int z = blockIdx.z;
  int t = threadIdx.x, lane = t&63, wid = t>>6;
  int q = wid & 3, kh = wid >> 2;
  int mtile = blockIdx.y*2 + (q&1);
  int ntile = blockIdx.x*2 + (q>>1);
  const u16* Ab = tiles + ((size_t)(mtile*24 + kh*12)*2*64 + lane)*8;
  const u16* Bb = tiles + (size_t)(EMB_SLOTS + z*W_SLOTS)*8
                        + ((size_t)(ntile*24 + kh*12)*2*64 + lane)*8;
  f32x4 acc00={0,0,0,0}, acc01={0,0,0,0}, acc10={0,0,0,0}, acc11={0,0,0,0};
  // slot strides in elems: frag=512, kchunk=1024
  bf16x8 a0 = *reinterpret_cast<const bf16x8*>(Ab);
  bf16x8 a1 = *reinterpret_cast<const bf16x8*>(Ab + 512);
  bf16x8 b0 = *reinterpret_cast<const bf16x8*>(Bb);
  bf16x8 b1 = *reinterpret_cast<const bf16x8*>(Bb + 512);
#pragma unroll
  for (int c=0;c<12;c++){
    bf16x8 na0, na1, nb0, nb1;
    if (c < 11){
      na0 = *reinterpret_cast<const bf16x8*>(Ab + (c+1)*1024);
      na1 = *reinterpret_cast<const bf16x8*>(Ab + (c+1)*1024 + 512);
      nb0 = *reinterpret_cast<const bf16x8*>(Bb + (c+1)*1024);
      nb1 = *reinterpret_cast<const bf16x8*>(Bb + (c+1)*1024 + 512);
    }
    acc00 = __builtin_amdgcn_mfma_f32_16x16x32_bf16(a0, b0, acc00, 0, 0, 0);
    acc10 = __builtin_amdgcn_mfma_f32_16x16x32_bf16(a1, b0, acc10, 0, 0, 0);
    acc01 = __builtin_amdgcn_mfma_f32_16x16x32_bf16(a0, b1, acc01, 0, 0, 0);
    acc11 = __builtin_amdgcn_mfma_f32_16x16x32_bf16(a1, b1, acc11, 0, 0, 0);
    a0 = na0; a1 = na1; b0 = nb0; b1 = nb1;
  }

  if (kh){
    red[q][0][lane] = acc00;
    red[q][1][lane] = acc01;
    red[q][2][lane] = acc10;
    red[q][3][lane] = acc11;
  }
  __syncthreads();
  if (!kh){
    acc00 += red[q][0][lane];
    acc01 += red[q][1][lane];
    acc10 += red[q][2][lane];
    acc11 += red[q][3][lane];
    int l15 = lane & 15;
    int r0 = (lane>>4)*4;
    int m0 = mtile*32, n0 = ntile*32;
    if (z < 4){
      u16* outp = ga.outH[z];
      float bn0 = 0.f, bn1 = 0.f;
      const float* b1f = ga.b1f[z];
      if (b1f){ bn0 = b1f[n0 + l15]; bn1 = b1f[n0 + 16 + l15]; }
#pragma unroll
      for (int r=0;r<4;r++){
        outp[(size_t)(m0 + r0 + r)*HDIM      + n0 + l15]      = f2h_bits(acc00[r] + bn0);
        outp[(size_t)(m0 + r0 + r)*HDIM      + n0 + 16 + l15] = f2h_bits(acc01[r] + bn1);
        outp[(size_t)(m0 + 16 + r0 + r)*HDIM + n0 + l15]      = f2h_bits(acc10[r] + bn0);
        outp[(size_t)(m0 + 16 + r0 + r)*HDIM + n0 + 16 + l15] = f2h_bits(acc11[r] + bn1);
      }
    } else {
      float* outp = ga.outF;
      float bn0 = ga.bsum[n0 + l15];
      float bn1 = ga.bsum[n0 + 16 + l15];
#pragma unroll
      for (int r=0;r<4;r++){
        outp[(size_t)(m0 + r0 + r)*HDIM      + n0 + l15]      = (acc00[r] + bn0)*0.125f;
        outp[(size_t)(m0 + r0 + r)*HDIM      + n0 + 16 + l15] = (acc01[r] + bn1)*0.125f;
        outp[(size_t)(m0 + 16 + r0 + r)*HDIM + n0 + l15]      = (acc10[r] + bn0)*0.125f;
        outp[(size_t)(m0 + 16 + r0 + r)*HDIM + n0 + 16 + l15] = (acc11[r] + bn1)*0.125f;
      }
    }
  }
}

// ---------------- pair4_k: 8 i x 8 j per wave; LDS L-read amortized over 8 j ----------------
// m[i,j] = sum_k relu(L'[i,k] + R[j,k]) * w2[k] + b2   (L' has b1 folded, f16)
struct P4Args {
  const u16* L[2]; const u16* R[2];
  const float* w2[2]; const float* b2[2];
  float* out[2];
};

__global__ __launch_bounds__(256) void pair4_k(P4Args pa){
  int z = blockIdx.z;
  int i0 = blockIdx.x*8, jt = blockIdx.y;   // grid (48, 12, 2)
  __shared__ u16 Lh[8][768];
  int t = threadIdx.x;
  const u16* __restrict__ L = pa.L[z];
  for (int idx=t; idx<1536; idx+=256){
    int ii = idx/192, qq = idx - ii*192;
    reinterpret_cast<ushort4*>(&Lh[ii][0])[qq] =
        reinterpret_cast<const ushort4*>(L + (size_t)(i0+ii)*HDIM)[qq];
  }
  int w = t>>6, l = t&63;
  // w2 as f16 pairs in registers: lane l covers kq = u*64+l (4 f16 each)
  uint2 w2r[3];
  {
    const float* w2f = pa.w2[z];
#pragma unroll
    for (int u=0;u<3;u++){
      float4 wv = *reinterpret_cast<const float4*>(w2f + (u*64+l)*4);
      w2r[u].x = pack2h(wv.x, wv.y);
      w2r[u].y = pack2h(wv.z, wv.w);
    }
  }
  int jb = jt*32 + w*8;
  const u16* __restrict__ R = pa.R[z];
  // load 8 j-rows' R fragments into registers: r[jj][u]
  uint2 rr[8][3];
#pragma unroll
  for (int jj=0;jj<8;jj++){
    const uint2* Rr = reinterpret_cast<const uint2*>(R + (size_t)(jb+jj)*HDIM);
#pragma unroll
    for (int u=0;u<3;u++) rr[jj][u] = Rr[u*64 + l];
  }
  __syncthreads();
  float acc[8][8];
#pragma unroll
  for (int ii=0;ii<8;ii++)
#pragma unroll
    for (int jj=0;jj<8;jj++) acc[ii][jj] = 0.f;

  const h2v hz = {(_Float16)0.f, (_Float16)0.f};
#pragma unroll
  for (int u=0;u<3;u++){
    h2v wA = __builtin_bit_cast(h2v, w2r[u].x);
    h2v wB = __builtin_bit_cast(h2v, w2r[u].y);
#pragma unroll
    for (int ii=0;ii<8;ii++){
      uint2 lv2 = reinterpret_cast<const uint2*>(&Lh[ii][0])[u*64 + l];
      h2v lA = __builtin_bit_cast(h2v, lv2.x);
      h2v lB = __builtin_bit_cast(h2v, lv2.y);
#pragma unroll
      for (int jj=0;jj<8;jj++){
        h2v sA = lA + __builtin_bit_cast(h2v, rr[jj][u].x);
        h2v sB = lB + __builtin_bit_cast(h2v, rr[jj][u].y);
        sA = __builtin_elementwise_max(sA, hz);
        sB = __builtin_elementwise_max(sB, hz);
        acc[ii][jj] = __builtin_amdgcn_fdot2(sA, wA, acc[ii][jj], false);
        acc[ii][jj] = __builtin_amdgcn_fdot2(sB, wB, acc[ii][jj], false);
      }
    }
  }
  // butterfly reduce all 64 accumulators; lane ii*8+jj writes its output
  float b2v = pa.b2[z][0];
  float* outp = pa.out[z];
#pragma unroll
  for (int ii=0;ii<8;ii++){
#pragma unroll
    for (int jj=0;jj<8;jj++){
      float a = acc[ii][jj];
#pragma unroll
      for (int m=32;m>=1;m>>=1) a += __shfl_xor(a, m, 64);
      if (l == ii*8 + jj){
        int i = i0 + ii, j = jb + jj;
        float v = a + b2v;
        if (i == j) v = 0.f;
        outp[(size_t)i*NTOT + j] = v;
      }
    }
  }
}

// ================= fallback (proven zero-ws path) =================
__global__ __launch_bounds__(256) void prop_k(
    const float* __restrict__ sup, const float* __restrict__ qry,
    const float* __restrict__ relW, const float* __restrict__ relB,
    float* __restrict__ outp){
  __shared__ float As[16][68];
  __shared__ float Bs[16][68];
  int t = threadIdx.x;
  int m0 = blockIdx.y*64, n0 = blockIdx.x*64;
  int lm = t>>2, lk = (t&3)<<2;
  int tx = t&15, ty = t>>4;
  float acc[4][4] = {{0,0,0,0},{0,0,0,0},{0,0,0,0},{0,0,0,0}};
  const float* Aptr = emb_row(sup, qry, m0+lm) + lk;
  const float* Bptr = relW + (size_t)(n0+lm)*HDIM + lk;
  for (int k0=0;k0<HDIM;k0+=16){
    float4 av = *reinterpret_cast<const float4*>(Aptr + k0);
    float4 bs = make_float4(0.f,0.f,0.f,0.f);
#pragma unroll
    for (int r=0;r<NREL;r++){
      float4 bv = *reinterpret_cast<const float4*>(Bptr + (size_t)r*WPLANE + k0);
      bs.x += bv.x; bs.y += bv.y; bs.z += bv.z; bs.w += bv.w;
    }
    __syncthreads();
    As[lk+0][lm]=av.x; As[lk+1][lm]=av.y; As[lk+2][lm]=av.z; As[lk+3][lm]=av.w;
    Bs[lk+0][lm]=bs.x; Bs[lk+1][lm]=bs.y; Bs[lk+2][lm]=bs.z; Bs[lk+3][lm]=bs.w;
    __syncthreads();
#pragma unroll
    for (int kk=0;kk<16;kk++){
      float4 a4 = *reinterpret_cast<const float4*>(&As[kk][ty<<2]);
      float4 b4 = *reinterpret_cast<const float4*>(&Bs[kk][tx<<2]);
      float ar[4]={a4.x,a4.y,a4.z,a4.w};
      float br[4]={b4.x,b4.y,b4.z,b4.w};
#pragma unroll
      for (int i2=0;i2<4;i2++)
#pragma unroll
        for (int j2=0;j2<4;j2++)
          acc[i2][j2] = fmaf(ar[i2], br[j2], acc[i2][j2]);
    }
  }
#pragma unroll
  for (int j2=0;j2<4;j2++){
    int n = n0 + (tx<<2) + j2;
    float bias = 0.f;
#pragma unroll
    for (int r=0;r<NREL;r++) bias += relB[r*HDIM + n];
#pragma unroll
    for (int i2=0;i2<4;i2++){
      int m = m0 + (ty<<2) + i2;
      outp[(size_t)m*HDIM + n] = (acc[i2][j2] + bias) * 0.125f;
    }
  }
}

struct NWArgs {
  const float* W1[2]; const float* b1[2]; const float* w2[2]; const float* b2[2];
  float* out[2];
};

__global__ __launch_bounds__(256) void pair_nows_k(
    const float* __restrict__ sup, const float* __restrict__ qry, NWArgs na){
  int z = blockIdx.z, i0 = blockIdx.x*32, j0 = blockIdx.y*32;
  __shared__ u16 Lt[32][768];
  __shared__ float Rj[768];
  __shared__ float b1s[768];
  __shared__ float w2s[768];
  const float* __restrict__ W1 = na.W1[z];
  int t = threadIdx.x;
  for (int k=t;k<768;k+=256){ b1s[k]=na.b1[z][k]; w2s[k]=na.w2[z][k]; }
  for (int e=t; e<32*768; e+=256){
    int ii = e/768, k = e - ii*768;
    const float4* er = reinterpret_cast<const float4*>(emb_row(sup, qry, i0+ii));
    const float4* wr = reinterpret_cast<const float4*>(W1 + (size_t)k*W1LD);
    float s = 0.f;
    for (int h=0;h<192;h++){
      float4 a = er[h], b = wr[h];
      s += a.x*b.x + a.y*b.y + a.z*b.z + a.w*b.w;
    }
    Lt[ii][k] = f2b(s);
  }
  float b2v = na.b2[z][0];
  int w = t>>6, l = t&63;
  float* outp = na.out[z];
  for (int jj=0;jj<32;jj++){
    int j = j0 + jj;
    const float4* ejr = reinterpret_cast<const float4*>(emb_row(sup, qry, j));
    __syncthreads();
    for (int k=t;k<768;k+=256){
      const float4* wr = reinterpret_cast<const float4*>(W1 + (size_t)k*W1LD + HDIM);
      float s = 0.f;
      for (int h=0;h<192;h++){
        float4 a = ejr[h], b = wr[h];
        s += a.x*b.x + a.y*b.y + a.z*b.z + a.w*b.w;
      }
      Rj[k] = s;
    }
    __syncthreads();
    for (int q=0;q<8;q++){
      int ii = (w<<3) + q;
      float acc = 0.f;
#pragma unroll
      for (int u=0;u<12;u++){
        int k = l + (u<<6);
        acc = fmaf(fmaxf(b2f(Lt[ii][k]) + Rj[k] + b1s[k], 0.f), w2s[k], acc);
      }
#pragma unroll
      for (int m=32;m>=1;m>>=1) acc += __shfl_xor(acc, m, 64);
      if (l==0){
        int i = i0 + ii;
        float v = acc + b2v;
        if (i==j) v = 0.f;
        outp[(size_t)i*NTOT + j] = v;
      }
    }
  }
}

extern "C" void kernel_launch(void* const* d_in, const int* in_sizes, int n_in,
                              void* d_out, int out_size, void* d_ws, size_t ws_size,
                              hipStream_t stream) {
  const float* sup   = (const float*)d_in[0];
  // d_in[1] = support_labels (unused)
  const float* qry   = (const float*)d_in[2];
  const float* simW1 = (const float*)d_in[3];
  const float* simb1 = (const float*)d_in[4];
  const float* simw2 = (const float*)d_in[5];
  const float* simb2 = (const float*)d_in[6];
  const float* divW1 = (const float*)d_in[7];
  const float* divb1 = (const float*)d_in[8];
  const float* divw2 = (const float*)d_in[9];
  const float* divb2 = (const float*)d_in[10];
  const float* relW  = (const float*)d_in[11];
  const float* relB  = (const float*)d_in[12];
  float* out = (float*)d_out;
  float* outSim = out + (size_t)NTOT*HDIM;
  float* outDiv = outSim + (size_t)NTOT*NTOT;

  const size_t TILB = (size_t)TILES_SLOTS*8*2;   // 6,488,064 B
  const size_t LRB  = (size_t)NTOT*HDIM*2;       //   589,824 B
  const size_t NEED = TILB + 4096 + 4*LRB;       // ~8.85 MB

  if (ws_size >= NEED){
    char* ws = (char*)d_ws;
    u16*   tiles = (u16*)(ws);
    float* bsum  = (float*)(ws + TILB);
    u16*   Ls    = (u16*)(ws + TILB + 4096);
    u16*   Rs    = (u16*)((char*)Ls + LRB);
    u16*   Ld    = (u16*)((char*)Rs + LRB);
    u16*   Rd    = (u16*)((char*)Ld + LRB);

    prep2_k<<<dim3((TILES_SLOTS + 255)/256), dim3(256), 0, stream>>>(
        sup, qry, relW, relB, simW1, divW1, tiles, bsum);

    G5M4 ga;
    ga.b1f[0]=simb1;   ga.outH[0]=Ls;
    ga.b1f[1]=nullptr; ga.outH[1]=Rs;
    ga.b1f[2]=divb1;   ga.outH[2]=Ld;
    ga.b1f[3]=nullptr; ga.outH[3]=Rd;
    ga.outF=out; ga.bsum=bsum;
    gemm5v4_k<<<dim3(12,6,5), dim3(512), 0, stream>>>(tiles, ga);

    P4Args pa;
    pa.L[0]=Ls; pa.R[0]=Rs; pa.w2[0]=simw2; pa.b2[0]=simb2; pa.out[0]=outSim;
    pa.L[1]=Ld; pa.R[1]=Rd; pa.w2[1]=divw2; pa.b2[1]=divb2; pa.out[1]=outDiv;
    pair4_k<<<dim3(48,12,2), dim3(256), 0, stream>>>(pa);
  } else {
    prop_k<<<dim3(12,6), dim3(256), 0, stream>>>(sup, qry, relW, relB, out);
    NWArgs na;
    na.W1[0]=simW1; na.b1[0]=simb1; na.w2[0]=simw2; na.b2[0]=simb2; na.out[0]=outSim;
    na.W1[1]=divW1; na.b1[1]=divb1; na.w2[1]=divw2; na.b2[1]=divb2; na.out[1]=outDiv;
    pair_nows_k<<<dim3(12,12,2), dim3(256), 0, stream>>>(sup, qry, na);
  }
}